// Round 12
// baseline (1596.867 us; speedup 1.0000x reference)
//
#include <hip/hip_runtime.h>
#include <math.h>

#define SDIM 1000
#define KPAD 1024
#define HDIM 200
#define MDIM 100
#define NPAD 208
#define TSTEPS 1024
#define BATCH 128
#define MT (BATCH*TSTEPS)
#define TOTX ((size_t)MT*(size_t)SDIM)

// ws layout: [0, 425984) WpT bf16 [208][1024]; [458752, +52428800) Z bf16 [131072][200]
#define Z_OFF 458752

typedef _Float16 half2_t __attribute__((ext_vector_type(2)));
typedef _Float16 f16x8 __attribute__((ext_vector_type(8)));
typedef __attribute__((ext_vector_type(8))) short short8;
typedef __attribute__((ext_vector_type(4))) float f32x4;

static __device__ __forceinline__ unsigned short f2bf(float f) {
    unsigned u = __float_as_uint(f);
    unsigned r = 0x7fffu + ((u >> 16) & 1u);   // RNE
    return (unsigned short)((u + r) >> 16);
}

// Raw workgroup barrier: drains ONLY lgkm (LDS); global ops stay in flight.
static __device__ __forceinline__ void wg_barrier() {
    asm volatile("s_waitcnt lgkmcnt(0)" ::: "memory");
    __builtin_amdgcn_s_barrier();
    asm volatile("" ::: "memory");
}

// ---------------------------------------------------------------------------
// Kernel 0: WpT[n][k] = relu(w_s[k]) * W1[k][n]  (bf16, transposed, padded)
// ---------------------------------------------------------------------------
__global__ __launch_bounds__(256) void prep_wpt(const float* __restrict__ w_s,
                                                const float* __restrict__ W1,
                                                unsigned short* __restrict__ wpt) {
    int idx = blockIdx.x * 256 + threadIdx.x;   // 208*1024 total
    int n = idx >> 10, k = idx & (KPAD - 1);
    float v = 0.f;
    if (n < HDIM && k < SDIM) {
        float ws = fmaxf(w_s[k], 0.f);
        v = ws * W1[k * HDIM + n];
    }
    wpt[idx] = f2bf(v);
}

// ---------------------------------------------------------------------------
// Kernel 1: Z = bf16(X) @ WpT^T.  BM=128 (4 waves x 2 m-tiles), BN=208, BK=32.
// (unchanged)
// ---------------------------------------------------------------------------
__global__ __launch_bounds__(256) void gemm_z(const float* __restrict__ X,
                                              const unsigned short* __restrict__ wpt,
                                              unsigned short* __restrict__ Z) {
    __shared__ __align__(16) unsigned short Abuf[2][128][40];
    __shared__ __align__(16) unsigned short Bbuf[2][13][16][40];
    const int t = threadIdx.x;
    const int m0 = blockIdx.x * 128;
    const int lane = t & 63, w = t >> 6;

    f32x4 acc[2][13];
#pragma unroll
    for (int mt = 0; mt < 2; ++mt)
#pragma unroll
        for (int i = 0; i < 13; ++i) acc[mt][i] = (f32x4){0.f, 0.f, 0.f, 0.f};

    auto stageA = [&](int bsel, int k0) {
        const int row = t >> 1, half = t & 1;
        size_t g = (size_t)(m0 + row) * SDIM + (size_t)(k0 + half * 16);
        float4 f0{}, f1{}, f2{}, f3{};
        if (g + 15 < TOTX) {
            f0 = *(const float4*)(X + g);      f1 = *(const float4*)(X + g + 4);
            f2 = *(const float4*)(X + g + 8);  f3 = *(const float4*)(X + g + 12);
        }
        short8 p0, p1;
        p0[0]=(short)f2bf(f0.x); p0[1]=(short)f2bf(f0.y); p0[2]=(short)f2bf(f0.z); p0[3]=(short)f2bf(f0.w);
        p0[4]=(short)f2bf(f1.x); p0[5]=(short)f2bf(f1.y); p0[6]=(short)f2bf(f1.z); p0[7]=(short)f2bf(f1.w);
        p1[0]=(short)f2bf(f2.x); p1[1]=(short)f2bf(f2.y); p1[2]=(short)f2bf(f2.z); p1[3]=(short)f2bf(f2.w);
        p1[4]=(short)f2bf(f3.x); p1[5]=(short)f2bf(f3.y); p1[6]=(short)f2bf(f3.z); p1[7]=(short)f2bf(f3.w);
        *(short8*)&Abuf[bsel][row][half * 16]     = p0;
        *(short8*)&Abuf[bsel][row][half * 16 + 8] = p1;
    };
    auto stageB = [&](int bsel, int k0) {
#pragma unroll
        for (int j = 0; j < 4; ++j) {
            int e = t + 256 * j;
            if (e < 832) {
                int n = e >> 2, q = e & 3;
                short8 v = *(const short8*)(wpt + (size_t)n * KPAD + k0 + q * 8);
                *(short8*)&Bbuf[bsel][n >> 4][n & 15][q * 8] = v;
            }
        }
    };

    stageA(0, 0);
    stageB(0, 0);
#pragma unroll 1
    for (int it = 0; it < 32; ++it) {
        __syncthreads();
        if (it + 1 < 32) { stageA((it + 1) & 1, (it + 1) * 32); stageB((it + 1) & 1, (it + 1) * 32); }
        const int bsel = it & 1;
        const short8 av0 = *(const short8*)&Abuf[bsel][w * 32 + (lane & 15)][(lane >> 4) * 8];
        const short8 av1 = *(const short8*)&Abuf[bsel][w * 32 + 16 + (lane & 15)][(lane >> 4) * 8];
#pragma unroll
        for (int nt = 0; nt < 13; ++nt) {
            const short8 bv = *(const short8*)&Bbuf[bsel][nt][lane & 15][(lane >> 4) * 8];
            acc[0][nt] = __builtin_amdgcn_mfma_f32_16x16x32_bf16(av0, bv, acc[0][nt], 0, 0, 0);
            acc[1][nt] = __builtin_amdgcn_mfma_f32_16x16x32_bf16(av1, bv, acc[1][nt], 0, 0, 0);
        }
    }

    const int colb = lane & 15;
#pragma unroll
    for (int mt = 0; mt < 2; ++mt) {
        const int rowb = m0 + w * 32 + mt * 16 + (lane >> 4) * 4;
#pragma unroll
        for (int nt = 0; nt < 13; ++nt) {
            int col = nt * 16 + colb;
            if (col < HDIM) {
#pragma unroll
                for (int r = 0; r < 4; ++r)
                    Z[(size_t)(rowb + r) * HDIM + col] = f2bf(acc[mt][nt][r]);
            }
        }
    }
}

// ---------------------------------------------------------------------------
// Kernel 2: MFMA scan. 1 WG (256 thr, 4 waves) per 16 batch elements -> 8 WGs.
// Transposed products so C/D layout (col=batch, row=idx) matches b64 LDS
// writes [batch][idx] and B-frag b128 reads (8 consecutive idx, fixed batch).
//   mm1: H^T[208x16] = W1b^T(kappa-folded,f16 regs)[208x128] @ M[128x16]
//        tiles: w0:0-3 w1:4-6 w2:7-9 w3:10-12; 4 ksteps.
//   y:   wave3, 1 tile [16x16] = Wy^T @ M (shares M frags) -> y_{st-1}.
//   mm2: M^T[112x16] = W2^T[112x224] @ H[224x16]; tiles w0:0-1 w1:2-3 w2:4-5
//        w3:6; 7 ksteps. tanh tail in f32 regs; m state in f32 regs.
// 2 lgkm-only barriers/step; single-buffered LDS (read-pre/write-post barrier).
// ---------------------------------------------------------------------------
#define MSTR 136     /* halfs; 272B row: 16B-aligned, 2-way banks (free) */
#define HSTR 232     /* halfs; 464B row: 16B-aligned, 2-way banks (free) */
#define KEXP 1.9235933878519513f   /* (4/3)*log2(e) */
#define KSF  0.81873075307798182f  /* exp(-1/5) */

__global__ __launch_bounds__(256, 1) void scan_mfma(
        const unsigned short* __restrict__ Z,
        const float* __restrict__ W1, const float* __restrict__ b1,
        const float* __restrict__ W2, const float* __restrict__ b2,
        const float* __restrict__ Wy, const float* __restrict__ by,
        float* __restrict__ out) {
    __shared__ __align__(16) _Float16 mbuf[16 * MSTR];   // m f16 [batch][m-idx pad 136]
    __shared__ __align__(16) _Float16 hbuf[16 * HSTR];   // h f16 [batch][h-idx pad 232]
    __shared__ float kap_s[128];

    const int t = threadIdx.x;
    const int bg = blockIdx.x;
    const int w = t >> 6, lane = t & 63;
    const int c = lane & 15, g = lane >> 4;

    if (t < 128) {
        float kv = 0.f;
        if (t < MDIM) {              // kappa_m in fp64 to match numpy
            double lg = 1.0000000434294482
                      + (double)t * ((2.9999999995657055 - 1.0000000434294482) / 99.0);
            double tau = exp(lg * 2.302585092994046);
            kv = (float)exp(-1.0 / tau);
        }
        kap_s[t] = kv;
    }
    for (int idx = t; idx < 16 * MSTR; idx += 256) mbuf[idx] = (_Float16)0.f;
    for (int idx = t; idx < 16 * HSTR; idx += 256) hbuf[idx] = (_Float16)0.f;
    __syncthreads();

    const int base1 = (w == 0) ? 0 : (1 + 3 * w);   // mm1 tiles: 0,4,7,10
    const int n1 = (w == 0) ? 4 : 3;
    const int base2 = 2 * w;                        // mm2 tiles: 0,2,4,6
    const int n2 = (w == 3) ? 1 : 2;
    const bool isw3 = (w == 3);

    // mm1 A-weights (kappa folded), b1, u state
    f16x8 w1f[4][4];
    float b1c[4][4];
    f32x4 u[4];
#pragma unroll
    for (int i = 0; i < 4; ++i) {
        const int T = base1 + i;
        const int n = 16 * T + c;
        const bool tv = (i < n1);
#pragma unroll
        for (int ks = 0; ks < 4; ++ks)
#pragma unroll
            for (int e = 0; e < 8; ++e) {
                int k = 32 * ks + 8 * g + e;
                float v = (tv && k < MDIM && n < HDIM)
                        ? kap_s[k] * W1[(SDIM + k) * HDIM + n] : 0.f;
                w1f[i][ks][e] = (_Float16)v;
            }
#pragma unroll
        for (int r = 0; r < 4; ++r) {
            int nr = 16 * T + 4 * g + r;
            b1c[i][r] = (tv && nr < HDIM) ? b1[nr] : 0.f;
        }
        u[i] = (f32x4){0.f, 0.f, 0.f, 0.f};
    }

    // mm2 A-weights + tanh consts + m state
    f16x8 w2f[2][7];
    float kapc[2][4], cmc[2][4], b2kc[2][4], mst[2][4];
#pragma unroll
    for (int j = 0; j < 2; ++j) {
        const int Tj = base2 + j;
        const int mj = 16 * Tj + c;
        const bool jv = (j < n2);
#pragma unroll
        for (int ks = 0; ks < 7; ++ks)
#pragma unroll
            for (int e = 0; e < 8; ++e) {
                int k = 32 * ks + 8 * g + e;
                float v = (jv && k < HDIM && mj < MDIM) ? W2[k * MDIM + mj] : 0.f;
                w2f[j][ks][e] = (_Float16)v;
            }
#pragma unroll
        for (int r = 0; r < 4; ++r) {
            int mr = 16 * Tj + 4 * g + r;
            bool mv = jv && (mr < MDIM);
            float kv = mv ? kap_s[mr] : 0.f;
            kapc[j][r] = kv;
            cmc[j][r]  = mv ? 3.f * (1.f - kv) : 0.f;
            b2kc[j][r] = mv ? b2[mr] * KEXP : 0.f;
            mst[j][r]  = 0.f;
        }
    }

    // y weights (wave 3)
    f16x8 wyf[4];
    float byc[4];
#pragma unroll
    for (int ks = 0; ks < 4; ++ks)
#pragma unroll
        for (int e = 0; e < 8; ++e) {
            int k = 32 * ks + 8 * g + e;
            wyf[ks][e] = (_Float16)((isw3 && c < 10 && k < MDIM) ? Wy[k * 10 + c] : 0.f);
        }
#pragma unroll
    for (int r = 0; r < 4; ++r) {
        int o = 4 * g + r;
        byc[r] = (isw3 && o < 10) ? by[o] : 0.f;
    }

    const unsigned short* Zc = Z + (size_t)(bg * 16 + c) * (TSTEPS * HDIM);
    float* outc = out + (size_t)(bg * 16 + c) * (TSTEPS * 10);

    uint2 zA[4], zB[4];
#pragma unroll
    for (int i = 0; i < 4; ++i) {
        const int n0 = 16 * (base1 + i) + 4 * g;
        const bool zv = (i < n1) && (n0 < HDIM);
        zA[i] = zv ? *(const uint2*)(Zc + 0 * HDIM + n0) : make_uint2(0u, 0u);
        zB[i] = zv ? *(const uint2*)(Zc + 1 * HDIM + n0) : make_uint2(0u, 0u);
    }
    __syncthreads();

    auto stepf = [&](uint2 (&zr)[4], const int st) {
        // ---- M fragments (m_{st-1}) ----
        f16x8 bm[4];
#pragma unroll
        for (int ks = 0; ks < 4; ++ks)
            bm[ks] = *(const f16x8*)(&mbuf[c * MSTR + 8 * g + 32 * ks]);

        // ---- u update (f32), acc init, z prefetch (2 ahead) ----
        f32x4 acc1[4];
#pragma unroll
        for (int i = 0; i < 4; ++i) {
            uint2 zv = zr[i];
            u[i][0] = fmaf(KSF, u[i][0], __uint_as_float(zv.x << 16));
            u[i][1] = fmaf(KSF, u[i][1], __uint_as_float(zv.x & 0xffff0000u));
            u[i][2] = fmaf(KSF, u[i][2], __uint_as_float(zv.y << 16));
            u[i][3] = fmaf(KSF, u[i][3], __uint_as_float(zv.y & 0xffff0000u));
            acc1[i][0] = u[i][0] + b1c[i][0];
            acc1[i][1] = u[i][1] + b1c[i][1];
            acc1[i][2] = u[i][2] + b1c[i][2];
            acc1[i][3] = u[i][3] + b1c[i][3];
            const int n0 = 16 * (base1 + i) + 4 * g;
            if ((i < n1) && (n0 < HDIM)) {
                int stn = st + 2; stn = (stn < TSTEPS) ? stn : TSTEPS - 1;
                zr[i] = *(const uint2*)(Zc + (size_t)stn * HDIM + n0);
            }
        }

        // ---- mm1 MFMAs ----
#pragma unroll
        for (int i = 0; i < 4; ++i) {
            if (i < n1) {
#pragma unroll
                for (int ks = 0; ks < 4; ++ks)
                    acc1[i] = __builtin_amdgcn_mfma_f32_16x16x32_f16(
                                  w1f[i][ks], bm[ks], acc1[i], 0, 0, 0);
            }
        }

        // ---- y_{st-1} on wave 3 (shares bm) ----
        if (isw3) {
            f32x4 ya = (f32x4){0.f, 0.f, 0.f, 0.f};
#pragma unroll
            for (int ks = 0; ks < 4; ++ks)
                ya = __builtin_amdgcn_mfma_f32_16x16x32_f16(wyf[ks], bm[ks], ya, 0, 0, 0);
            if (st > 0) {
#pragma unroll
                for (int r = 0; r < 4; ++r) {
                    int o = 4 * g + r;
                    if (o < 10)
                        outc[(size_t)(st - 1) * 10 + o] = ya[r] + byc[r];
                }
            }
        }

        // ---- relu, pack f16, write H ----
#pragma unroll
        for (int i = 0; i < 4; ++i) {
            if (i < n1) {
                unsigned p0 = __builtin_bit_cast(unsigned,
                    __builtin_amdgcn_cvt_pkrtz(fmaxf(acc1[i][0], 0.f), fmaxf(acc1[i][1], 0.f)));
                unsigned p1 = __builtin_bit_cast(unsigned,
                    __builtin_amdgcn_cvt_pkrtz(fmaxf(acc1[i][2], 0.f), fmaxf(acc1[i][3], 0.f)));
                *(uint2*)(&hbuf[c * HSTR + 16 * (base1 + i) + 4 * g]) = make_uint2(p0, p1);
            }
        }
        wg_barrier();

        // ---- H fragments + mm2 MFMAs + tanh tail + write M ----
        f16x8 bh[7];
#pragma unroll
        for (int ks = 0; ks < 7; ++ks)
            bh[ks] = *(const f16x8*)(&hbuf[c * HSTR + 8 * g + 32 * ks]);
#pragma unroll
        for (int j = 0; j < 2; ++j) {
            if (j < n2) {
                f32x4 a2 = (f32x4){0.f, 0.f, 0.f, 0.f};
#pragma unroll
                for (int ks = 0; ks < 7; ++ks)
                    a2 = __builtin_amdgcn_mfma_f32_16x16x32_f16(w2f[j][ks], bh[ks], a2, 0, 0, 0);
#pragma unroll
                for (int r = 0; r < 4; ++r) {
                    float E = __builtin_amdgcn_exp2f(fmaf(a2[r], KEXP, b2kc[j][r]));
                    float dm = 1.7159f - 3.4318f * __builtin_amdgcn_rcpf(E + 1.f);
                    mst[j][r] = fmaf(kapc[j][r], mst[j][r], cmc[j][r] * dm);
                }
                unsigned q0 = __builtin_bit_cast(unsigned,
                    __builtin_amdgcn_cvt_pkrtz(mst[j][0], mst[j][1]));
                unsigned q1 = __builtin_bit_cast(unsigned,
                    __builtin_amdgcn_cvt_pkrtz(mst[j][2], mst[j][3]));
                *(uint2*)(&mbuf[c * MSTR + 16 * (base2 + j) + 4 * g]) = make_uint2(q0, q1);
            }
        }
        wg_barrier();
    };

#pragma unroll 1
    for (int st = 0; st < TSTEPS; st += 2) {
        stepf(zA, st);
        stepf(zB, st + 1);
    }

    // tail: y_{1023} from final m
    if (isw3) {
        f16x8 bm[4];
#pragma unroll
        for (int ks = 0; ks < 4; ++ks)
            bm[ks] = *(const f16x8*)(&mbuf[c * MSTR + 8 * g + 32 * ks]);
        f32x4 ya = (f32x4){0.f, 0.f, 0.f, 0.f};
#pragma unroll
        for (int ks = 0; ks < 4; ++ks)
            ya = __builtin_amdgcn_mfma_f32_16x16x32_f16(wyf[ks], bm[ks], ya, 0, 0, 0);
#pragma unroll
        for (int r = 0; r < 4; ++r) {
            int o = 4 * g + r;
            if (o < 10)
                outc[(size_t)(TSTEPS - 1) * 10 + o] = ya[r] + byc[r];
        }
    }
}

extern "C" void kernel_launch(void* const* d_in, const int* in_sizes, int n_in,
                              void* d_out, int out_size, void* d_ws, size_t ws_size,
                              hipStream_t stream) {
    const float* X  = (const float*)d_in[0];
    const float* ws = (const float*)d_in[1];
    const float* W1 = (const float*)d_in[2];
    const float* b1 = (const float*)d_in[3];
    const float* W2 = (const float*)d_in[4];
    const float* b2 = (const float*)d_in[5];
    const float* Wy = (const float*)d_in[6];
    const float* by = (const float*)d_in[7];
    float* out = (float*)d_out;

    unsigned short* wpt = (unsigned short*)d_ws;
    unsigned short* Z   = (unsigned short*)((char*)d_ws + Z_OFF);

    hipLaunchKernelGGL(prep_wpt, dim3((NPAD * KPAD) / 256), dim3(256), 0, stream, ws, W1, wpt);
    hipLaunchKernelGGL(gemm_z, dim3(MT / 128), dim3(256), 0, stream, X, wpt, Z);
    hipLaunchKernelGGL(scan_mfma, dim3(BATCH / 16), dim3(256), 0, stream,
                       Z, W1, b1, W2, b2, Wy, by, out);
}